// Round 18
// baseline (354.758 us; speedup 1.0000x reference)
//
#include <hip/hip_runtime.h>
#include <hip/hip_fp16.h>
#include <math.h>

#define NN 10000
#define EE 160000
#define DPB 8   // dsts per k_accum block

#define RS128 0.08838834764831845f   // 1/sqrt(128)
#define RS384 0.05103103630798287f   // 1/sqrt(384)
#define RS32  0.17677669529663687f   // 1/sqrt(32)
#define R3    0.57735026918962576f   // 1/sqrt(3)
#define C1V   0.86602540378443865f   // sqrt(3)/2

typedef _Float16 half8 __attribute__((ext_vector_type(8)));
typedef _Float16 half4 __attribute__((ext_vector_type(4)));
typedef float f32x4 __attribute__((ext_vector_type(4)));

__device__ __forceinline__ float sspf(float x) {
    return fmaxf(x, 0.0f) + log1pf(__expf(-fabsf(x))) - 0.69314718055994530942f;
}

__device__ __forceinline__ void packone(const float* __restrict__ W,
                                        _Float16* __restrict__ P,
                                        int K, int N, int off) {
    const int KS = K >> 5;
    int j = off & 7, lane = (off >> 3) & 63, rest = off >> 9;
    int ks = rest % KS, ct = rest / KS;
    int k = ks * 32 + ((lane >> 4) << 3) + j;
    int c = ct * 16 + (lane & 15);
    P[off] = (_Float16)W[k * N + c];
}

// ---- ALL weight packing + deg/cursor zeroing in one launch ----
__global__ __launch_bounds__(256) void k_packall(
    const float* __restrict__ Wp0, const float* __restrict__ Wp1,
    const float* __restrict__ Wn0, const float* __restrict__ Wn1,
    const float* __restrict__ Wo0, const float* __restrict__ Wo1,
    const float* __restrict__ ngW1, const float* __restrict__ ngW2,
    const float* __restrict__ l0W1, const float* __restrict__ fcnW1,
    const float* __restrict__ fcnW2, const float* __restrict__ l0W2,
    _Float16* __restrict__ pWp0, _Float16* __restrict__ pWp1,
    _Float16* __restrict__ pWn0, _Float16* __restrict__ pWn1,
    _Float16* __restrict__ pWo0, _Float16* __restrict__ pWo1,
    _Float16* __restrict__ png1, _Float16* __restrict__ png2,
    _Float16* __restrict__ pWc, _Float16* __restrict__ pWa,
    _Float16* __restrict__ Wf_t, _Float16* __restrict__ Wl_t,
    _Float16* __restrict__ pWab, int* __restrict__ degz) {
    int idx = blockIdx.x * 256 + threadIdx.x;
    if (idx < 98304) {
        int seg = idx >> 14, off = idx & 16383;
        if (seg == 0) packone(Wp0, pWp0, 128, 128, off);
        else if (seg == 1) packone(Wp1, pWp1, 128, 128, off);
        else if (seg == 2) packone(Wn0, pWn0, 128, 128, off);
        else if (seg == 3) packone(Wn1, pWn1, 128, 128, off);
        else if (seg == 4) packone(Wo0, pWo0, 128, 128, off);
        else packone(Wo1, pWo1, 128, 128, off);
    } else if (idx < 229376) {
        int r = idx - 98304;
        if (r < 65536) packone(ngW1, png1, 256, 256, r);
        else packone(ngW2, png2, 256, 256, r - 65536);
    } else if (idx < 233472) {
        packone(l0W1 + 256 * 32, pWc, 128, 32, idx - 229376);
    } else if (idx < 234496) {
        packone(fcnW1, pWa, 32, 32, idx - 233472);
    } else if (idx < 250880) {
        int off = idx - 234496;   // [0, 16384)
        int k = off & 31, c = off >> 5;
        Wf_t[c * 32 + k] = (_Float16)fcnW2[k * 512 + c];
        Wl_t[c * 32 + k] = (_Float16)l0W2[k * 512 + c];
    } else if (idx < 259072) {
        int off = idx - 250880;   // [0, 8192): pWab K=128, N=64 = [pA | pB]
        int j = off & 7, lane = (off >> 3) & 63, rest = off >> 9;
        int ks = rest & 3, ct = rest >> 2;
        int k = ks * 32 + ((lane >> 4) << 3) + j;
        int c = ct * 16 + (lane & 15);
        pWab[off] = (_Float16)((c < 32) ? l0W1[k * 32 + c]
                                        : l0W1[(128 + k) * 32 + (c - 32)]);
    } else if (idx < 279072) {
        degz[idx - 259072] = 0;   // deg + cursor (2*NN contiguous)
    }
}

// ---- FUSED node kernel: irrep(Wp)->prexv_h fp16 (+pAB) + norm_gate + irrep(Wn)->selfx_h ----
__global__ __launch_bounds__(256) void k_node(
    const float* __restrict__ X,
    const _Float16* __restrict__ pWp0, const float* __restrict__ bp0,
    const _Float16* __restrict__ pWp1, const _Float16* __restrict__ pWab,
    const _Float16* __restrict__ png1, const float* __restrict__ ngb1,
    const _Float16* __restrict__ png2, const float* __restrict__ ngb2,
    const _Float16* __restrict__ pWn0, const float* __restrict__ bn0,
    const _Float16* __restrict__ pWn1,
    _Float16* __restrict__ prexv_h, float* __restrict__ pAB,
    _Float16* __restrict__ selfx_h) {
    __shared__ _Float16 f0h[16][264];     // [0:128]=x_s, [128:256]=norms; later g
    __shared__ _Float16 t1h[16][264];     // prex_s stash for pAB; then t1
    __shared__ _Float16 xvh[3][16][136];
    __shared__ _Float16 pvh[3][16][136];  // prex vector stash
    const int t = threadIdx.x, lane = t & 63, w = t >> 6;
    const int nb = blockIdx.x * 16;
    const int row16 = lane & 15, kg = lane >> 4;
    const f32x4 zero = {0.0f, 0.0f, 0.0f, 0.0f};

    for (int idx = t; idx < 16 * 128; idx += 256) {
        int n = idx >> 7, c4 = idx & 127;
        const float4 v = *(const float4*)(X + (size_t)(nb + n) * 512 + 4 * c4);
        float vals[4] = {v.x, v.y, v.z, v.w};
        int c = 4 * c4;
#pragma unroll
        for (int j = 0; j < 4; ++j) {
            int cc = c + j;
            if (cc < 128) f0h[n][cc] = (_Float16)vals[j];
            else { int d = cc - 128; xvh[d % 3][n][d / 3] = (_Float16)vals[j]; }
        }
    }
    __syncthreads();
    for (int idx = t; idx < 16 * 128; idx += 256) {
        int n = idx >> 7, u = idx & 127;
        float a = (float)xvh[0][n][u], b = (float)xvh[1][n][u], c = (float)xvh[2][n][u];
        f0h[n][128 + u] = (_Float16)sqrtf(fmaf(a, a, fmaf(b, b, fmaf(c, c, 1e-12f))));
    }
    __syncthreads();
    // irrep(Wp): wave 0 -> prex_s into t1h; waves 1-3 -> prex_v into pvh
    {
        const _Float16* pW = (w == 0) ? pWp0 : pWp1;
        f32x4 acc[8];
#pragma unroll
        for (int ct = 0; ct < 8; ++ct) acc[ct] = zero;
        for (int ks = 0; ks < 4; ++ks) {
            const half8 a = (w == 0)
                ? *(const half8*)&f0h[row16][ks * 32 + kg * 8]
                : *(const half8*)&xvh[w - 1][row16][ks * 32 + kg * 8];
#pragma unroll
            for (int ct = 0; ct < 8; ++ct) {
                const half8 b = *(const half8*)(pW + (((ct * 4 + ks) * 64 + lane) << 3));
                acc[ct] = __builtin_amdgcn_mfma_f32_16x16x32_f16(a, b, acc[ct], 0, 0, 0);
            }
        }
#pragma unroll
        for (int ct = 0; ct < 8; ++ct) {
            const int col = ct * 16 + row16;
            const float bb = (w == 0) ? bp0[col] : 0.0f;
#pragma unroll
            for (int r = 0; r < 4; ++r) {
                const int n = kg * 4 + r;
                const float val = acc[ct][r] * RS128 + bb;
                if (w == 0) t1h[n][col] = (_Float16)val;
                else pvh[w - 1][n][col] = (_Float16)val;
            }
        }
    }
    __syncthreads();
    // pAB = prex_s @ [l0W1[0:128] | l0W1[128:256]]
    {
        f32x4 acc = zero;
#pragma unroll
        for (int ks = 0; ks < 4; ++ks) {
            const half8 a = *(const half8*)&t1h[row16][ks * 32 + kg * 8];
            const half8 b = *(const half8*)(pWab + (((w * 4 + ks) * 64 + lane) << 3));
            acc = __builtin_amdgcn_mfma_f32_16x16x32_f16(a, b, acc, 0, 0, 0);
        }
        const int col = w * 16 + row16;
#pragma unroll
        for (int r = 0; r < 4; ++r)
            pAB[(size_t)(nb + kg * 4 + r) * 64 + col] = acc[r];
    }
    for (int idx = t; idx < 16 * 128; idx += 256) {
        int n = idx >> 7, u = idx & 127;
        half4 pv = {pvh[0][n][u], pvh[1][n][u], pvh[2][n][u], t1h[n][u]};
        *(half4*)(prexv_h + (size_t)(nb + n) * 512 + (u << 2)) = pv;
    }
    __syncthreads();
    // MLP1
    {
        f32x4 acc[4];
#pragma unroll
        for (int i = 0; i < 4; ++i) acc[i] = zero;
        for (int ks = 0; ks < 8; ++ks) {
            const half8 a = *(const half8*)&f0h[row16][ks * 32 + kg * 8];
#pragma unroll
            for (int c2 = 0; c2 < 4; ++c2) {
                const int ct = 4 * w + c2;
                const half8 b = *(const half8*)(png1 + (((ct * 8 + ks) * 64 + lane) << 3));
                acc[c2] = __builtin_amdgcn_mfma_f32_16x16x32_f16(a, b, acc[c2], 0, 0, 0);
            }
        }
        __syncthreads();
#pragma unroll
        for (int c2 = 0; c2 < 4; ++c2) {
            const int col = (4 * w + c2) * 16 + row16;
            const float bb = ngb1[col];
#pragma unroll
            for (int r = 0; r < 4; ++r) {
                const float z = acc[c2][r] + bb;
                t1h[kg * 4 + r][col] = (_Float16)(z / (1.0f + __expf(-z)));
            }
        }
    }
    __syncthreads();
    // MLP2
    {
        f32x4 acc[4];
#pragma unroll
        for (int i = 0; i < 4; ++i) acc[i] = zero;
        for (int ks = 0; ks < 8; ++ks) {
            const half8 a = *(const half8*)&t1h[row16][ks * 32 + kg * 8];
#pragma unroll
            for (int c2 = 0; c2 < 4; ++c2) {
                const int ct = 4 * w + c2;
                const half8 b = *(const half8*)(png2 + (((ct * 8 + ks) * 64 + lane) << 3));
                acc[c2] = __builtin_amdgcn_mfma_f32_16x16x32_f16(a, b, acc[c2], 0, 0, 0);
            }
        }
        __syncthreads();
#pragma unroll
        for (int c2 = 0; c2 < 4; ++c2) {
            const int col = (4 * w + c2) * 16 + row16;
            const float bb = ngb2[col];
#pragma unroll
            for (int r = 0; r < 4; ++r)
                f0h[kg * 4 + r][col] = (_Float16)(acc[c2][r] + bb);
        }
    }
    __syncthreads();
    for (int idx = t; idx < 16 * 128; idx += 256) {
        int n = idx >> 7, u = idx & 127;
        const _Float16 g = f0h[n][128 + u];
        xvh[0][n][u] = xvh[0][n][u] * g;
        xvh[1][n][u] = xvh[1][n][u] * g;
        xvh[2][n][u] = xvh[2][n][u] * g;
    }
    __syncthreads();
    // irrep(Wn) -> selfx_h
    {
        const _Float16* pw = (w == 0) ? pWn0 : pWn1;
        f32x4 acc[8];
#pragma unroll
        for (int ct = 0; ct < 8; ++ct) acc[ct] = zero;
        for (int ks = 0; ks < 4; ++ks) {
            const half8 a = (w == 0)
                ? *(const half8*)&f0h[row16][ks * 32 + kg * 8]
                : *(const half8*)&xvh[w - 1][row16][ks * 32 + kg * 8];
#pragma unroll
            for (int ct = 0; ct < 8; ++ct) {
                const half8 b = *(const half8*)(pw + (((ct * 4 + ks) * 64 + lane) << 3));
                acc[ct] = __builtin_amdgcn_mfma_f32_16x16x32_f16(a, b, acc[ct], 0, 0, 0);
            }
        }
#pragma unroll
        for (int ct = 0; ct < 8; ++ct) {
            const int col = ct * 16 + row16;
            const float bb = (w == 0) ? bn0[col] : 0.0f;
#pragma unroll
            for (int r = 0; r < 4; ++r) {
                const int n = kg * 4 + r;
                const float val = acc[ct][r] * RS128 + bb;
                if (w == 0) f0h[n][col] = (_Float16)val;
                else xvh[w - 1][n][col] = (_Float16)val;
            }
        }
    }
    __syncthreads();
    for (int idx = t; idx < 16 * 128; idx += 256) {
        int n = idx >> 7, u = idx & 127;
        half4 sx = {f0h[n][u], xvh[0][n][u], xvh[1][n][u], xvh[2][n][u]};
        *(half4*)(selfx_h + (size_t)(nb + n) * 512 + (u << 2)) = sx;
    }
}

// ---- CSR build ----
__global__ __launch_bounds__(256) void k_deg(const int* __restrict__ ei, int* __restrict__ deg) {
    int e = blockIdx.x * 256 + threadIdx.x;
    if (e < EE) atomicAdd(&deg[ei[e]], 1);
}

__global__ __launch_bounds__(1024) void k_scan(const int* __restrict__ deg, int* __restrict__ row_ptr) {
    __shared__ int part[1024];
    const int t = threadIdx.x;
    const int base = t * 10;
    int loc[10];
    int s = 0;
#pragma unroll
    for (int i = 0; i < 10; ++i) {
        int idx = base + i;
        int d = (idx < NN) ? deg[idx] : 0;
        loc[i] = s;
        s += d;
    }
    part[t] = s;
    __syncthreads();
    for (int off = 1; off < 1024; off <<= 1) {
        int v = (t >= off) ? part[t - off] : 0;
        __syncthreads();
        part[t] += v;
        __syncthreads();
    }
    int excl = (t > 0) ? part[t - 1] : 0;
#pragma unroll
    for (int i = 0; i < 10; ++i) {
        int idx = base + i;
        if (idx <= NN) row_ptr[idx] = excl + loc[i];
    }
}

// fill csr_eid + CSR-ordered src and sh(half4) side tables
__global__ __launch_bounds__(256) void k_fill(const int* __restrict__ ei,
                                              const float* __restrict__ edge_sh,
                                              const int* __restrict__ row_ptr,
                                              int* __restrict__ cursor,
                                              int* __restrict__ csr_eid,
                                              int* __restrict__ csr_src,
                                              _Float16* __restrict__ csr_sh) {
    int e = blockIdx.x * 256 + threadIdx.x;
    if (e < EE) {
        int d = ei[e];
        int s = ei[EE + e];
        const float4 sh = *(const float4*)(edge_sh + (size_t)e * 4);
        int pos = row_ptr[d] + atomicAdd(&cursor[d], 1);
        csr_eid[pos] = e;
        csr_src[pos] = s;
        half4 h = {(_Float16)sh.x, (_Float16)sh.y, (_Float16)sh.z, (_Float16)sh.w};
        *(half4*)(csr_sh + (size_t)pos * 4) = h;
    }
}

// ---- MFMA hidden units, CSR-position order; fp16 prexv gathers ----
__global__ __launch_bounds__(256) void k_hidden_m(
    const _Float16* __restrict__ prexv_h, const float* __restrict__ pAB,
    const int* __restrict__ edge_index, const float* __restrict__ edge_attr,
    const int* __restrict__ csr_eid,
    const _Float16* __restrict__ pWc, const _Float16* __restrict__ pWa,
    __half* __restrict__ hh) {
    const int pb = blockIdx.x * 32;
    const int t = threadIdx.x, lane = t & 63, w = t >> 6;
    __shared__ _Float16 ipl[32][132];
    __shared__ _Float16 eal[32][36];
    __shared__ _Float16 h1o[32][32];
    __shared__ _Float16 hao[32][32];
    __shared__ int dsts[32], srcs[32], eids[32];

    if (t < 32) {
        const int id = csr_eid[pb + t];
        eids[t] = id;
        dsts[t] = edge_index[id];
        srcs[t] = edge_index[EE + id];
    }
    __syncthreads();
    for (int idx = t; idx < 32 * 32; idx += 256) {
        int e = idx >> 5, j = idx & 31;
        eal[e][j] = (_Float16)edge_attr[(size_t)eids[e] * 32 + j];
    }
    for (int idx = t; idx < 32 * 128; idx += 256) {
        int e = idx >> 7, u = idx & 127;
        const half4 pd = *(const half4*)(prexv_h + (size_t)dsts[e] * 512 + (u << 2));
        const half4 ps = *(const half4*)(prexv_h + (size_t)srcs[e] * 512 + (u << 2));
        const float ipv = (float)pd.x * (float)ps.x + (float)pd.y * (float)ps.y +
                          (float)pd.z * (float)ps.z;
        ipl[e][u] = (_Float16)(ipv * R3);
    }
    __syncthreads();

    const int row16 = lane & 15, kg = lane >> 4;
    const int mt = w >> 1, ct = w & 1;
    const int e0 = mt * 16;
    const f32x4 zero = {0.0f, 0.0f, 0.0f, 0.0f};
    const int kc = ct * 16 + row16;

    {
        f32x4 acc = zero;
#pragma unroll
        for (int ks = 0; ks < 4; ++ks) {
            const half8 a = *(const half8*)&ipl[e0 + row16][ks * 32 + kg * 8];
            const half8 b = *(const half8*)(pWc + (((ct * 4 + ks) * 64 + lane) << 3));
            acc = __builtin_amdgcn_mfma_f32_16x16x32_f16(a, b, acc, 0, 0, 0);
        }
#pragma unroll
        for (int r = 0; r < 4; ++r) {
            const int e = e0 + kg * 4 + r;
            const float v = acc[r] + pAB[(size_t)dsts[e] * 64 + kc]
                                   + pAB[(size_t)srcs[e] * 64 + 32 + kc];
            h1o[e][kc] = (_Float16)sspf(v * RS384);
        }
    }
    {
        const half8 a = *(const half8*)&eal[e0 + row16][kg * 8];
        const half8 b = *(const half8*)(pWa + ((ct * 64 + lane) << 3));
        f32x4 acc = __builtin_amdgcn_mfma_f32_16x16x32_f16(a, b, zero, 0, 0, 0);
#pragma unroll
        for (int r = 0; r < 4; ++r) {
            const int e = e0 + kg * 4 + r;
            hao[e][kc] = (_Float16)sspf((float)acc[r] * RS32);
        }
    }
    __syncthreads();
    for (int idx = t; idx < 32 * 32; idx += 256) {
        const int e = idx >> 5, j = idx & 31;
        unsigned vv;
        if (j < 16) {
            __half2 h2 = __halves2half2((__half)h1o[e][2 * j], (__half)h1o[e][2 * j + 1]);
            vv = *(unsigned*)&h2;
        } else {
            const int jj = j - 16;
            __half2 h2 = __halves2half2((__half)hao[e][2 * jj], (__half)hao[e][2 * jj + 1]);
            vv = *(unsigned*)&h2;
        }
        ((unsigned*)hh)[(size_t)(pb + e) * 32 + j] = vv;
    }
}

// ---- per-dst accumulate via MFMA; 1-hop payload prefetch + fused irrep(Wo) tail ----
__global__ __launch_bounds__(512) void k_accum(
    const __half* __restrict__ hh, const _Float16* __restrict__ selfx_h,
    const int* __restrict__ row_ptr,
    const int* __restrict__ csr_src, const _Float16* __restrict__ csr_sh,
    const _Float16* __restrict__ Wf_t, const _Float16* Wl_t,  // Wl_t: no restrict (keep loads in-loop)
    const _Float16* __restrict__ pWo0, const float* __restrict__ bo0,
    const _Float16* __restrict__ pWo1,
    float* __restrict__ outacc) {
    const int dst0 = blockIdx.x * DPB;
    const int t = threadIdx.x;
    const int lane = t & 63;
    const int wid = t >> 6;
    const int lcol = lane & 15;
    const int kg = lane >> 4;
    const int u = 16 * wid + lcol;
    const int koff = kg * 8;

    __shared__ __align__(16) _Float16 h1s[2][4][16][8];
    __shared__ __align__(16) _Float16 has[2][4][16][8];
    __shared__ __align__(8) _Float16 shl[2][16][4];
    __shared__ int cbeg[DPB], cne[DPB], cchk[DPB + 1];
    __shared__ __align__(16) _Float16 accP[4][16][136];   // planes s,vx,vy,vz; rows 8..15 stay 0

    if (t < DPB) {
        const int b = row_ptr[dst0 + t];
        cbeg[t] = b;
        cne[t] = row_ptr[dst0 + t + 1] - b;
    }
    for (int idx = t; idx < 4 * 16 * 136; idx += 512)
        ((_Float16*)accP)[idx] = (_Float16)0;
    __syncthreads();
    if (t == 0) {
        int s = 0;
#pragma unroll
        for (int i = 0; i < DPB; ++i) { cchk[i] = s; s += max(1, (cne[i] + 15) >> 4); }
        cchk[DPB] = s;
    }
    // only Wf fragments register-cached; Wl streamed per chunk (VGPR budget)
    half8 bf[4];
#pragma unroll
    for (int q = 0; q < 4; ++q)
        bf[q] = *(const half8*)(Wf_t + (q * 128 + u) * 32 + koff);
    __syncthreads();
    const int nc = cchk[DPB];
    const float inv32 = 1.0f / 32.0f;

    float acc0 = 0, acc1 = 0, acc2 = 0, acc3 = 0;

    unsigned rhh = 0;
    const half4 h4z = {(_Float16)0, (_Float16)0, (_Float16)0, (_Float16)0};
    half4 rsh4 = h4z;
    half4 nsx[4] = {h4z, h4z, h4z, h4z};

    const int se = t >> 5, sw = t & 31;

    auto chunkmeta = [&](int ci, int& pos, int& ce) {
        int dd = 0;
        while (dd + 1 < DPB && ci >= cchk[dd + 1]) ++dd;
        const int c0 = (ci - cchk[dd]) << 4;
        ce = min(16, cne[dd] - c0);
        pos = cbeg[dd] + c0;
    };

    auto issue_meta = [&](int ci) {
        int pos, ce; chunkmeta(ci, pos, ce);
        rhh = (se < ce) ? ((const unsigned*)hh)[(size_t)(pos + se) * 32 + sw] : 0u;
        if (t < 16)
            rsh4 = (t < ce) ? *(const half4*)(csr_sh + (size_t)(pos + t) * 4) : h4z;
    };

    auto issue_payload = [&](int ci) {
        int pos, ce; chunkmeta(ci, pos, ce);
#pragma unroll
        for (int r = 0; r < 4; ++r) {
            const int e = kg * 4 + r;
            if (e < ce) {
                const int s = csr_src[pos + e];
                nsx[r] = *(const half4*)(selfx_h + (size_t)s * 512 + (u << 2));
            } else {
                nsx[r] = h4z;
            }
        }
    };

    auto flush = [&](int dd) {
        acc0 += __shfl_xor(acc0, 16, 64); acc0 += __shfl_xor(acc0, 32, 64);
        acc1 += __shfl_xor(acc1, 16, 64); acc1 += __shfl_xor(acc1, 32, 64);
        acc2 += __shfl_xor(acc2, 16, 64); acc2 += __shfl_xor(acc2, 32, 64);
        acc3 += __shfl_xor(acc3, 16, 64); acc3 += __shfl_xor(acc3, 32, 64);
        if (lane < 16) {
            const size_t g = (size_t)(dst0 + dd) * 512;
            const half4 sx = *(const half4*)(selfx_h + g + (u << 2));
            accP[0][dd][u] = (_Float16)(acc0 + (float)sx.x);
            accP[1][dd][u] = (_Float16)(acc1 + (float)sx.y);
            accP[2][dd][u] = (_Float16)(acc2 + (float)sx.z);
            accP[3][dd][u] = (_Float16)(acc3 + (float)sx.w);
        }
        acc0 = acc1 = acc2 = acc3 = 0;
    };

    issue_meta(0);
    issue_payload(0);
    int cur = 0, cur_dd = 0;
    for (int ci = 0; ci < nc; ++ci) {
        // commit staged meta into LDS[cur]
        if (sw < 16) ((unsigned*)h1s[cur])[(sw >> 2) * 64 + se * 4 + (sw & 3)] = rhh;
        else         ((unsigned*)has[cur])[((sw - 16) >> 2) * 64 + se * 4 + ((sw - 16) & 3)] = rhh;
        if (t < 16) *(half4*)&shl[cur][t][0] = rsh4;
        int dd = 0;
        while (dd + 1 < DPB && ci >= cchk[dd + 1]) ++dd;
        if (ci + 1 < nc) issue_meta(ci + 1);
        __syncthreads();
        if (dd != cur_dd) { flush(cur_dd); cur_dd = dd; }

        const half8 haf = *(const half8*)(&has[cur][kg][lcol][0]);
        const half8 h1f = *(const half8*)(&h1s[cur][kg][lcol][0]);
        const f32x4 zero = {0.0f, 0.0f, 0.0f, 0.0f};
        f32x4 A[4], B[4];
#pragma unroll
        for (int q = 0; q < 4; ++q) {
            const half8 blq = *(const half8*)(Wl_t + (q * 128 + u) * 32 + koff);
            A[q] = __builtin_amdgcn_mfma_f32_16x16x32_f16(haf, bf[q], zero, 0, 0, 0);
            B[q] = __builtin_amdgcn_mfma_f32_16x16x32_f16(h1f, blq, zero, 0, 0, 0);
        }
#pragma unroll
        for (int r = 0; r < 4; ++r) {
            const int e = kg * 4 + r;
            const float w1 = A[0][r] * B[0][r] * inv32;
            const float w2 = A[1][r] * B[1][r] * inv32;
            const float w3 = A[2][r] * B[2][r] * inv32;
            const float w4 = A[3][r] * B[3][r] * inv32;
            const half4 shv = *(const half4*)&shl[cur][e][0];
            const float sh0 = (float)shv.x, s1x = (float)shv.y;
            const float s1y = (float)shv.z, s1z = (float)shv.w;
            const float xs0 = (float)nsx[r].x;
            const float xv0 = (float)nsx[r].y;
            const float xv1 = (float)nsx[r].z;
            const float xv2 = (float)nsx[r].w;
            const float dv = xv0 * s1x + xv1 * s1y + xv2 * s1z;
            acc0 += 0.5f * (w1 * xs0 * sh0 + w4 * dv * R3);   // dead slots: payload 0 -> 0
            acc1 += C1V * (w2 * xs0 * s1x + w3 * xv0 * sh0);
            acc2 += C1V * (w2 * xs0 * s1y + w3 * xv1 * sh0);
            acc3 += C1V * (w2 * xs0 * s1z + w3 * xv2 * sh0);
        }
        // prefetch next chunk's payload (lands during commit+barrier+MFMA of ci+1)
        if (ci + 1 < nc) issue_payload(ci + 1);
        cur ^= 1;
    }
    flush(cur_dd);
    __syncthreads();

    // fused final irrep(Wo): M=16 (rows 8..15 zero), wave -> (matrix, col-tile half)
    {
        const int m = wid >> 1;
        const int ctg = (wid & 1) * 4;
        const _Float16* pW = (m == 0) ? pWo0 : pWo1;
        const f32x4 zero = {0.0f, 0.0f, 0.0f, 0.0f};
        f32x4 acc[4];
#pragma unroll
        for (int i = 0; i < 4; ++i) acc[i] = zero;
        for (int ks = 0; ks < 4; ++ks) {
            const half8 a = *(const half8*)&accP[m][lcol][ks * 32 + koff];
#pragma unroll
            for (int c2 = 0; c2 < 4; ++c2) {
                const int ct = ctg + c2;
                const half8 b = *(const half8*)(pW + (((ct * 4 + ks) * 64 + lane) << 3));
                acc[c2] = __builtin_amdgcn_mfma_f32_16x16x32_f16(a, b, acc[c2], 0, 0, 0);
            }
        }
#pragma unroll
        for (int c2 = 0; c2 < 4; ++c2) {
            const int col = (ctg + c2) * 16 + lcol;
            const float bb = (m == 0) ? bo0[col] : 0.0f;
#pragma unroll
            for (int r = 0; r < 4; ++r) {
                const int row = kg * 4 + r;
                if (row < DPB) {
                    const size_t g = (size_t)(dst0 + row) * 512;
                    const float val = acc[c2][r] * RS128 + bb;
                    if (m == 0) outacc[g + col] = val;
                    else outacc[g + 128 + 3 * col + (m - 1)] = val;
                }
            }
        }
    }
}

extern "C" void kernel_launch(void* const* d_in, const int* in_sizes, int n_in,
                              void* d_out, int out_size, void* d_ws, size_t ws_size,
                              hipStream_t stream) {
    const float* x = (const float*)d_in[0];
    const int* edge_index = (const int*)d_in[1];
    const float* edge_attr = (const float*)d_in[2];
    const float* edge_sh = (const float*)d_in[3];
    const float* Wp0 = (const float*)d_in[4];
    const float* bp0 = (const float*)d_in[5];
    const float* Wp1 = (const float*)d_in[6];
    const float* ngW1 = (const float*)d_in[7];
    const float* ngb1 = (const float*)d_in[8];
    const float* ngW2 = (const float*)d_in[9];
    const float* ngb2 = (const float*)d_in[10];
    const float* Wn0 = (const float*)d_in[11];
    const float* bn0 = (const float*)d_in[12];
    const float* Wn1 = (const float*)d_in[13];
    const float* fcnW1 = (const float*)d_in[14];
    const float* fcnW2 = (const float*)d_in[15];
    const float* l0W1 = (const float*)d_in[16];
    const float* l0W2 = (const float*)d_in[17];
    const float* Wo0 = (const float*)d_in[18];
    const float* bo0 = (const float*)d_in[19];
    const float* Wo1 = (const float*)d_in[20];

    float* out = (float*)d_out;
    _Float16* prexv_h = (_Float16*)d_out;    // first 10MB of d_out; dead before k_accum writes
    _Float16* selfx_h = (_Float16*)d_ws;     // [NN][128][4] interleaved
    int* deg = (int*)(selfx_h + (size_t)NN * 512);
    int* cursor = deg + NN;
    int* row_ptr = cursor + NN;
    int* csr_eid = row_ptr + NN + 1;
    int* csr_src = csr_eid + EE;
    _Float16* csr_sh = (_Float16*)(csr_src + EE);
    float* pAB = (float*)(csr_sh + (size_t)EE * 4);
    __half* hh = (__half*)(pAB + (size_t)NN * 64);
    _Float16* Wf_t = (_Float16*)(hh + (size_t)EE * 64);
    _Float16* Wl_t = Wf_t + 512 * 32;
    _Float16* pWp0 = Wl_t + 512 * 32;
    _Float16* pWp1 = pWp0 + 128 * 128;
    _Float16* pWn0 = pWp1 + 128 * 128;
    _Float16* pWn1 = pWn0 + 128 * 128;
    _Float16* pWo0 = pWn1 + 128 * 128;
    _Float16* pWo1 = pWo0 + 128 * 128;
    _Float16* png1 = pWo1 + 128 * 128;
    _Float16* png2 = png1 + 256 * 256;
    _Float16* pWc  = png2 + 256 * 256;
    _Float16* pWa  = pWc + 128 * 32;
    _Float16* pWab = pWa + 32 * 32;

    k_packall<<<1091, 256, 0, stream>>>(Wp0, Wp1, Wn0, Wn1, Wo0, Wo1, ngW1, ngW2,
                                        l0W1, fcnW1, fcnW2, l0W2,
                                        pWp0, pWp1, pWn0, pWn1, pWo0, pWo1,
                                        png1, png2, pWc, pWa, Wf_t, Wl_t,
                                        pWab, deg);

    k_node<<<NN / 16, 256, 0, stream>>>(x, pWp0, bp0, pWp1, pWab,
                                        png1, ngb1, png2, ngb2, pWn0, bn0, pWn1,
                                        prexv_h, pAB, selfx_h);
    k_deg<<<EE / 256, 256, 0, stream>>>(edge_index, deg);
    k_scan<<<1, 1024, 0, stream>>>(deg, row_ptr);
    k_fill<<<EE / 256, 256, 0, stream>>>(edge_index, edge_sh, row_ptr, cursor,
                                         csr_eid, csr_src, csr_sh);
    k_hidden_m<<<EE / 32, 256, 0, stream>>>(prexv_h, pAB, edge_index, edge_attr, csr_eid,
                                            pWc, pWa, hh);
    k_accum<<<NN / DPB, 512, 0, stream>>>(hh, selfx_h, row_ptr, csr_src, csr_sh,
                                          Wf_t, Wl_t, pWo0, bo0, pWo1, out);
}

// Round 19
// 285.364 us; speedup vs baseline: 1.2432x; 1.2432x over previous
//
#include <hip/hip_runtime.h>
#include <hip/hip_fp16.h>
#include <math.h>

#define NN 10000
#define EE 160000
#define DPB 16   // dsts per k_accum block

#define RS128 0.08838834764831845f   // 1/sqrt(128)
#define RS384 0.05103103630798287f   // 1/sqrt(384)
#define RS32  0.17677669529663687f   // 1/sqrt(32)
#define R3    0.57735026918962576f   // 1/sqrt(3)
#define C1V   0.86602540378443865f   // sqrt(3)/2

typedef _Float16 half8 __attribute__((ext_vector_type(8)));
typedef _Float16 half4 __attribute__((ext_vector_type(4)));
typedef float f32x4 __attribute__((ext_vector_type(4)));

__device__ __forceinline__ float sspf(float x) {
    return fmaxf(x, 0.0f) + log1pf(__expf(-fabsf(x))) - 0.69314718055994530942f;
}

__device__ __forceinline__ void packone(const float* __restrict__ W,
                                        _Float16* __restrict__ P,
                                        int K, int N, int off) {
    const int KS = K >> 5;
    int j = off & 7, lane = (off >> 3) & 63, rest = off >> 9;
    int ks = rest % KS, ct = rest / KS;
    int k = ks * 32 + ((lane >> 4) << 3) + j;
    int c = ct * 16 + (lane & 15);
    P[off] = (_Float16)W[k * N + c];
}

// ---- ALL weight packing + deg/cursor zeroing in one launch ----
__global__ __launch_bounds__(256) void k_packall(
    const float* __restrict__ Wp0, const float* __restrict__ Wp1,
    const float* __restrict__ Wn0, const float* __restrict__ Wn1,
    const float* __restrict__ Wo0, const float* __restrict__ Wo1,
    const float* __restrict__ ngW1, const float* __restrict__ ngW2,
    const float* __restrict__ l0W1, const float* __restrict__ fcnW1,
    const float* __restrict__ fcnW2, const float* __restrict__ l0W2,
    _Float16* __restrict__ pWp0, _Float16* __restrict__ pWp1,
    _Float16* __restrict__ pWn0, _Float16* __restrict__ pWn1,
    _Float16* __restrict__ pWo0, _Float16* __restrict__ pWo1,
    _Float16* __restrict__ png1, _Float16* __restrict__ png2,
    _Float16* __restrict__ pWc, _Float16* __restrict__ pWa,
    _Float16* __restrict__ Wf_t, _Float16* __restrict__ Wl_t,
    _Float16* __restrict__ pWab, int* __restrict__ degz) {
    int idx = blockIdx.x * 256 + threadIdx.x;
    if (idx < 98304) {
        int seg = idx >> 14, off = idx & 16383;
        if (seg == 0) packone(Wp0, pWp0, 128, 128, off);
        else if (seg == 1) packone(Wp1, pWp1, 128, 128, off);
        else if (seg == 2) packone(Wn0, pWn0, 128, 128, off);
        else if (seg == 3) packone(Wn1, pWn1, 128, 128, off);
        else if (seg == 4) packone(Wo0, pWo0, 128, 128, off);
        else packone(Wo1, pWo1, 128, 128, off);
    } else if (idx < 229376) {
        int r = idx - 98304;
        if (r < 65536) packone(ngW1, png1, 256, 256, r);
        else packone(ngW2, png2, 256, 256, r - 65536);
    } else if (idx < 233472) {
        packone(l0W1 + 256 * 32, pWc, 128, 32, idx - 229376);
    } else if (idx < 234496) {
        packone(fcnW1, pWa, 32, 32, idx - 233472);
    } else if (idx < 250880) {
        int off = idx - 234496;   // [0, 16384)
        int k = off & 31, c = off >> 5;
        Wf_t[c * 32 + k] = (_Float16)fcnW2[k * 512 + c];
        Wl_t[c * 32 + k] = (_Float16)l0W2[k * 512 + c];
    } else if (idx < 259072) {
        int off = idx - 250880;   // [0, 8192): pWab K=128, N=64 = [pA | pB]
        int j = off & 7, lane = (off >> 3) & 63, rest = off >> 9;
        int ks = rest & 3, ct = rest >> 2;
        int k = ks * 32 + ((lane >> 4) << 3) + j;
        int c = ct * 16 + (lane & 15);
        pWab[off] = (_Float16)((c < 32) ? l0W1[k * 32 + c]
                                        : l0W1[(128 + k) * 32 + (c - 32)]);
    } else if (idx < 279072) {
        degz[idx - 259072] = 0;   // deg + cursor (2*NN contiguous)
    }
}

// ---- FUSED node kernel: irrep(Wp)->prexv_h fp16 (+pAB) + norm_gate + irrep(Wn)->selfx_h ----
__global__ __launch_bounds__(256) void k_node(
    const float* __restrict__ X,
    const _Float16* __restrict__ pWp0, const float* __restrict__ bp0,
    const _Float16* __restrict__ pWp1, const _Float16* __restrict__ pWab,
    const _Float16* __restrict__ png1, const float* __restrict__ ngb1,
    const _Float16* __restrict__ png2, const float* __restrict__ ngb2,
    const _Float16* __restrict__ pWn0, const float* __restrict__ bn0,
    const _Float16* __restrict__ pWn1,
    _Float16* __restrict__ prexv_h, float* __restrict__ pAB,
    _Float16* __restrict__ selfx_h) {
    __shared__ _Float16 f0h[16][264];
    __shared__ _Float16 t1h[16][264];
    __shared__ _Float16 xvh[3][16][136];
    __shared__ _Float16 pvh[3][16][136];
    const int t = threadIdx.x, lane = t & 63, w = t >> 6;
    const int nb = blockIdx.x * 16;
    const int row16 = lane & 15, kg = lane >> 4;
    const f32x4 zero = {0.0f, 0.0f, 0.0f, 0.0f};

    for (int idx = t; idx < 16 * 128; idx += 256) {
        int n = idx >> 7, c4 = idx & 127;
        const float4 v = *(const float4*)(X + (size_t)(nb + n) * 512 + 4 * c4);
        float vals[4] = {v.x, v.y, v.z, v.w};
        int c = 4 * c4;
#pragma unroll
        for (int j = 0; j < 4; ++j) {
            int cc = c + j;
            if (cc < 128) f0h[n][cc] = (_Float16)vals[j];
            else { int d = cc - 128; xvh[d % 3][n][d / 3] = (_Float16)vals[j]; }
        }
    }
    __syncthreads();
    for (int idx = t; idx < 16 * 128; idx += 256) {
        int n = idx >> 7, u = idx & 127;
        float a = (float)xvh[0][n][u], b = (float)xvh[1][n][u], c = (float)xvh[2][n][u];
        f0h[n][128 + u] = (_Float16)sqrtf(fmaf(a, a, fmaf(b, b, fmaf(c, c, 1e-12f))));
    }
    __syncthreads();
    {
        const _Float16* pW = (w == 0) ? pWp0 : pWp1;
        f32x4 acc[8];
#pragma unroll
        for (int ct = 0; ct < 8; ++ct) acc[ct] = zero;
        for (int ks = 0; ks < 4; ++ks) {
            const half8 a = (w == 0)
                ? *(const half8*)&f0h[row16][ks * 32 + kg * 8]
                : *(const half8*)&xvh[w - 1][row16][ks * 32 + kg * 8];
#pragma unroll
            for (int ct = 0; ct < 8; ++ct) {
                const half8 b = *(const half8*)(pW + (((ct * 4 + ks) * 64 + lane) << 3));
                acc[ct] = __builtin_amdgcn_mfma_f32_16x16x32_f16(a, b, acc[ct], 0, 0, 0);
            }
        }
#pragma unroll
        for (int ct = 0; ct < 8; ++ct) {
            const int col = ct * 16 + row16;
            const float bb = (w == 0) ? bp0[col] : 0.0f;
#pragma unroll
            for (int r = 0; r < 4; ++r) {
                const int n = kg * 4 + r;
                const float val = acc[ct][r] * RS128 + bb;
                if (w == 0) t1h[n][col] = (_Float16)val;
                else pvh[w - 1][n][col] = (_Float16)val;
            }
        }
    }
    __syncthreads();
    {
        f32x4 acc = zero;
#pragma unroll
        for (int ks = 0; ks < 4; ++ks) {
            const half8 a = *(const half8*)&t1h[row16][ks * 32 + kg * 8];
            const half8 b = *(const half8*)(pWab + (((w * 4 + ks) * 64 + lane) << 3));
            acc = __builtin_amdgcn_mfma_f32_16x16x32_f16(a, b, acc, 0, 0, 0);
        }
        const int col = w * 16 + row16;
#pragma unroll
        for (int r = 0; r < 4; ++r)
            pAB[(size_t)(nb + kg * 4 + r) * 64 + col] = acc[r];
    }
    for (int idx = t; idx < 16 * 128; idx += 256) {
        int n = idx >> 7, u = idx & 127;
        half4 pv = {pvh[0][n][u], pvh[1][n][u], pvh[2][n][u], t1h[n][u]};
        *(half4*)(prexv_h + (size_t)(nb + n) * 512 + (u << 2)) = pv;
    }
    __syncthreads();
    {
        f32x4 acc[4];
#pragma unroll
        for (int i = 0; i < 4; ++i) acc[i] = zero;
        for (int ks = 0; ks < 8; ++ks) {
            const half8 a = *(const half8*)&f0h[row16][ks * 32 + kg * 8];
#pragma unroll
            for (int c2 = 0; c2 < 4; ++c2) {
                const int ct = 4 * w + c2;
                const half8 b = *(const half8*)(png1 + (((ct * 8 + ks) * 64 + lane) << 3));
                acc[c2] = __builtin_amdgcn_mfma_f32_16x16x32_f16(a, b, acc[c2], 0, 0, 0);
            }
        }
        __syncthreads();
#pragma unroll
        for (int c2 = 0; c2 < 4; ++c2) {
            const int col = (4 * w + c2) * 16 + row16;
            const float bb = ngb1[col];
#pragma unroll
            for (int r = 0; r < 4; ++r) {
                const float z = acc[c2][r] + bb;
                t1h[kg * 4 + r][col] = (_Float16)(z / (1.0f + __expf(-z)));
            }
        }
    }
    __syncthreads();
    {
        f32x4 acc[4];
#pragma unroll
        for (int i = 0; i < 4; ++i) acc[i] = zero;
        for (int ks = 0; ks < 8; ++ks) {
            const half8 a = *(const half8*)&t1h[row16][ks * 32 + kg * 8];
#pragma unroll
            for (int c2 = 0; c2 < 4; ++c2) {
                const int ct = 4 * w + c2;
                const half8 b = *(const half8*)(png2 + (((ct * 8 + ks) * 64 + lane) << 3));
                acc[c2] = __builtin_amdgcn_mfma_f32_16x16x32_f16(a, b, acc[c2], 0, 0, 0);
            }
        }
        __syncthreads();
#pragma unroll
        for (int c2 = 0; c2 < 4; ++c2) {
            const int col = (4 * w + c2) * 16 + row16;
            const float bb = ngb2[col];
#pragma unroll
            for (int r = 0; r < 4; ++r)
                f0h[kg * 4 + r][col] = (_Float16)(acc[c2][r] + bb);
        }
    }
    __syncthreads();
    for (int idx = t; idx < 16 * 128; idx += 256) {
        int n = idx >> 7, u = idx & 127;
        const _Float16 g = f0h[n][128 + u];
        xvh[0][n][u] = xvh[0][n][u] * g;
        xvh[1][n][u] = xvh[1][n][u] * g;
        xvh[2][n][u] = xvh[2][n][u] * g;
    }
    __syncthreads();
    {
        const _Float16* pw = (w == 0) ? pWn0 : pWn1;
        f32x4 acc[8];
#pragma unroll
        for (int ct = 0; ct < 8; ++ct) acc[ct] = zero;
        for (int ks = 0; ks < 4; ++ks) {
            const half8 a = (w == 0)
                ? *(const half8*)&f0h[row16][ks * 32 + kg * 8]
                : *(const half8*)&xvh[w - 1][row16][ks * 32 + kg * 8];
#pragma unroll
            for (int ct = 0; ct < 8; ++ct) {
                const half8 b = *(const half8*)(pw + (((ct * 4 + ks) * 64 + lane) << 3));
                acc[ct] = __builtin_amdgcn_mfma_f32_16x16x32_f16(a, b, acc[ct], 0, 0, 0);
            }
        }
#pragma unroll
        for (int ct = 0; ct < 8; ++ct) {
            const int col = ct * 16 + row16;
            const float bb = (w == 0) ? bn0[col] : 0.0f;
#pragma unroll
            for (int r = 0; r < 4; ++r) {
                const int n = kg * 4 + r;
                const float val = acc[ct][r] * RS128 + bb;
                if (w == 0) f0h[n][col] = (_Float16)val;
                else xvh[w - 1][n][col] = (_Float16)val;
            }
        }
    }
    __syncthreads();
    for (int idx = t; idx < 16 * 128; idx += 256) {
        int n = idx >> 7, u = idx & 127;
        half4 sx = {f0h[n][u], xvh[0][n][u], xvh[1][n][u], xvh[2][n][u]};
        *(half4*)(selfx_h + (size_t)(nb + n) * 512 + (u << 2)) = sx;
    }
}

// ---- CSR build ----
__global__ __launch_bounds__(256) void k_deg(const int* __restrict__ ei, int* __restrict__ deg) {
    int e = blockIdx.x * 256 + threadIdx.x;
    if (e < EE) atomicAdd(&deg[ei[e]], 1);
}

__global__ __launch_bounds__(1024) void k_scan(const int* __restrict__ deg, int* __restrict__ row_ptr) {
    __shared__ int part[1024];
    const int t = threadIdx.x;
    const int base = t * 10;
    int loc[10];
    int s = 0;
#pragma unroll
    for (int i = 0; i < 10; ++i) {
        int idx = base + i;
        int d = (idx < NN) ? deg[idx] : 0;
        loc[i] = s;
        s += d;
    }
    part[t] = s;
    __syncthreads();
    for (int off = 1; off < 1024; off <<= 1) {
        int v = (t >= off) ? part[t - off] : 0;
        __syncthreads();
        part[t] += v;
        __syncthreads();
    }
    int excl = (t > 0) ? part[t - 1] : 0;
#pragma unroll
    for (int i = 0; i < 10; ++i) {
        int idx = base + i;
        if (idx <= NN) row_ptr[idx] = excl + loc[i];
    }
}

__global__ __launch_bounds__(256) void k_fill(const int* __restrict__ ei,
                                              const int* __restrict__ row_ptr,
                                              int* __restrict__ cursor,
                                              int* __restrict__ csr_eid) {
    int e = blockIdx.x * 256 + threadIdx.x;
    if (e < EE) {
        int d = ei[e];
        int pos = atomicAdd(&cursor[d], 1);
        csr_eid[row_ptr[d] + pos] = e;
    }
}

// ---- MFMA hidden units, CSR-position order; fp16 prexv gathers ----
__global__ __launch_bounds__(256) void k_hidden_m(
    const _Float16* __restrict__ prexv_h, const float* __restrict__ pAB,
    const int* __restrict__ edge_index, const float* __restrict__ edge_attr,
    const int* __restrict__ csr_eid,
    const _Float16* __restrict__ pWc, const _Float16* __restrict__ pWa,
    __half* __restrict__ hh) {
    const int pb = blockIdx.x * 32;
    const int t = threadIdx.x, lane = t & 63, w = t >> 6;
    __shared__ _Float16 ipl[32][132];
    __shared__ _Float16 eal[32][36];
    __shared__ _Float16 h1o[32][32];
    __shared__ _Float16 hao[32][32];
    __shared__ int dsts[32], srcs[32], eids[32];

    if (t < 32) {
        const int id = csr_eid[pb + t];
        eids[t] = id;
        dsts[t] = edge_index[id];
        srcs[t] = edge_index[EE + id];
    }
    __syncthreads();
    for (int idx = t; idx < 32 * 32; idx += 256) {
        int e = idx >> 5, j = idx & 31;
        eal[e][j] = (_Float16)edge_attr[(size_t)eids[e] * 32 + j];
    }
    for (int idx = t; idx < 32 * 128; idx += 256) {
        int e = idx >> 7, u = idx & 127;
        const half4 pd = *(const half4*)(prexv_h + (size_t)dsts[e] * 512 + (u << 2));
        const half4 ps = *(const half4*)(prexv_h + (size_t)srcs[e] * 512 + (u << 2));
        const float ipv = (float)pd.x * (float)ps.x + (float)pd.y * (float)ps.y +
                          (float)pd.z * (float)ps.z;
        ipl[e][u] = (_Float16)(ipv * R3);
    }
    __syncthreads();

    const int row16 = lane & 15, kg = lane >> 4;
    const int mt = w >> 1, ct = w & 1;
    const int e0 = mt * 16;
    const f32x4 zero = {0.0f, 0.0f, 0.0f, 0.0f};
    const int kc = ct * 16 + row16;

    {
        f32x4 acc = zero;
#pragma unroll
        for (int ks = 0; ks < 4; ++ks) {
            const half8 a = *(const half8*)&ipl[e0 + row16][ks * 32 + kg * 8];
            const half8 b = *(const half8*)(pWc + (((ct * 4 + ks) * 64 + lane) << 3));
            acc = __builtin_amdgcn_mfma_f32_16x16x32_f16(a, b, acc, 0, 0, 0);
        }
#pragma unroll
        for (int r = 0; r < 4; ++r) {
            const int e = e0 + kg * 4 + r;
            const float v = acc[r] + pAB[(size_t)dsts[e] * 64 + kc]
                                   + pAB[(size_t)srcs[e] * 64 + 32 + kc];
            h1o[e][kc] = (_Float16)sspf(v * RS384);
        }
    }
    {
        const half8 a = *(const half8*)&eal[e0 + row16][kg * 8];
        const half8 b = *(const half8*)(pWa + ((ct * 64 + lane) << 3));
        f32x4 acc = __builtin_amdgcn_mfma_f32_16x16x32_f16(a, b, zero, 0, 0, 0);
#pragma unroll
        for (int r = 0; r < 4; ++r) {
            const int e = e0 + kg * 4 + r;
            hao[e][kc] = (_Float16)sspf((float)acc[r] * RS32);
        }
    }
    __syncthreads();
    for (int idx = t; idx < 32 * 32; idx += 256) {
        const int e = idx >> 5, j = idx & 31;
        unsigned vv;
        if (j < 16) {
            __half2 h2 = __halves2half2((__half)h1o[e][2 * j], (__half)h1o[e][2 * j + 1]);
            vv = *(unsigned*)&h2;
        } else {
            const int jj = j - 16;
            __half2 h2 = __halves2half2((__half)hao[e][2 * jj], (__half)hao[e][2 * jj + 1]);
            vv = *(unsigned*)&h2;
        }
        ((unsigned*)hh)[(size_t)(pb + e) * 32 + j] = vv;
    }
}

// ---- per-dst accumulate via MFMA (r17 pipeline, DPB=16) + fused irrep(Wo) tail ----
__global__ __launch_bounds__(512) void k_accum(
    const __half* __restrict__ hh, const _Float16* __restrict__ selfx_h,
    const int* __restrict__ edge_index, const float* __restrict__ edge_sh,
    const int* __restrict__ row_ptr, const int* __restrict__ csr_eid,
    const _Float16* __restrict__ Wf_t, const _Float16* __restrict__ Wl_t,
    const _Float16* __restrict__ pWo0, const float* __restrict__ bo0,
    const _Float16* __restrict__ pWo1,
    float* __restrict__ outacc) {
    const int dst0 = blockIdx.x * DPB;
    const int t = threadIdx.x;
    const int lane = t & 63;
    const int wid = t >> 6;
    const int lcol = lane & 15;
    const int kg = lane >> 4;
    const int u = 16 * wid + lcol;
    const int koff = kg * 8;

    __shared__ __align__(16) _Float16 h1s[2][4][16][8];
    __shared__ __align__(16) _Float16 has[2][4][16][8];
    __shared__ float shl[2][16][4];
    __shared__ int srcs[2][16];
    __shared__ int cbeg[DPB], cne[DPB], cchk[DPB + 1];
    __shared__ __align__(16) _Float16 accP[4][16][136];   // planes s,vx,vy,vz

    if (t < DPB) {
        const int b = row_ptr[dst0 + t];
        cbeg[t] = b;
        cne[t] = row_ptr[dst0 + t + 1] - b;
    }
    __syncthreads();
    if (t == 0) {
        int s = 0;
#pragma unroll
        for (int i = 0; i < DPB; ++i) { cchk[i] = s; s += max(1, (cne[i] + 15) >> 4); }
        cchk[DPB] = s;
    }
    half8 bf[4], bl[4];
#pragma unroll
    for (int q = 0; q < 4; ++q) {
        const int col = q * 128 + u;
        bf[q] = *(const half8*)(Wf_t + col * 32 + koff);
        bl[q] = *(const half8*)(Wl_t + col * 32 + koff);
    }
    __syncthreads();
    const int nc = cchk[DPB];
    const float inv32 = 1.0f / 32.0f;

    float acc0 = 0, acc1 = 0, acc2 = 0, acc3 = 0;

    unsigned rhh = 0;
    int rsrc = 0;
    float4 rsh = {0.0f, 0.0f, 0.0f, 0.0f};

    const int se = t >> 5, sw = t & 31;

    auto issue = [&](int ci) {
        int dd = 0;
        while (dd + 1 < DPB && ci >= cchk[dd + 1]) ++dd;
        const int c0 = (ci - cchk[dd]) << 4;
        const int ce = min(16, cne[dd] - c0);
        const int pos = cbeg[dd] + c0;
        rhh = (se < ce) ? ((const unsigned*)hh)[(size_t)(pos + se) * 32 + sw] : 0u;
        if (t < 16) {
            if (t < ce) {
                const int id = csr_eid[pos + t];
                rsrc = edge_index[EE + id];
                rsh = *(const float4*)(edge_sh + (size_t)id * 4);
            } else {
                rsrc = 0;
                rsh = make_float4(0.0f, 0.0f, 0.0f, 0.0f);
            }
        }
    };

    auto flush = [&](int dd) {
        acc0 += __shfl_xor(acc0, 16, 64); acc0 += __shfl_xor(acc0, 32, 64);
        acc1 += __shfl_xor(acc1, 16, 64); acc1 += __shfl_xor(acc1, 32, 64);
        acc2 += __shfl_xor(acc2, 16, 64); acc2 += __shfl_xor(acc2, 32, 64);
        acc3 += __shfl_xor(acc3, 16, 64); acc3 += __shfl_xor(acc3, 32, 64);
        if (lane < 16) {
            const size_t g = (size_t)(dst0 + dd) * 512;
            const half4 sx = *(const half4*)(selfx_h + g + (u << 2));
            accP[0][dd][u] = (_Float16)(acc0 + (float)sx.x);
            accP[1][dd][u] = (_Float16)(acc1 + (float)sx.y);
            accP[2][dd][u] = (_Float16)(acc2 + (float)sx.z);
            accP[3][dd][u] = (_Float16)(acc3 + (float)sx.w);
        }
        acc0 = acc1 = acc2 = acc3 = 0;
    };

    issue(0);
    int cur = 0, cur_dd = 0;
    for (int ci = 0; ci < nc; ++ci) {
        if (sw < 16) ((unsigned*)h1s[cur])[(sw >> 2) * 64 + se * 4 + (sw & 3)] = rhh;
        else         ((unsigned*)has[cur])[((sw - 16) >> 2) * 64 + se * 4 + ((sw - 16) & 3)] = rhh;
        if (t < 16) {
            srcs[cur][t] = rsrc;
            shl[cur][t][0] = rsh.x; shl[cur][t][1] = rsh.y;
            shl[cur][t][2] = rsh.z; shl[cur][t][3] = rsh.w;
        }
        int dd = 0;
        while (dd + 1 < DPB && ci >= cchk[dd + 1]) ++dd;
        const int c0 = (ci - cchk[dd]) << 4;
        const int ce = min(16, cne[dd] - c0);
        if (ci + 1 < nc) issue(ci + 1);
        __syncthreads();
        if (dd != cur_dd) { flush(cur_dd); cur_dd = dd; }

        const half8 haf = *(const half8*)(&has[cur][kg][lcol][0]);
        const half8 h1f = *(const half8*)(&h1s[cur][kg][lcol][0]);
        const f32x4 zero = {0.0f, 0.0f, 0.0f, 0.0f};
        f32x4 A[4], B[4];
#pragma unroll
        for (int q = 0; q < 4; ++q) {
            A[q] = __builtin_amdgcn_mfma_f32_16x16x32_f16(haf, bf[q], zero, 0, 0, 0);
            B[q] = __builtin_amdgcn_mfma_f32_16x16x32_f16(h1f, bl[q], zero, 0, 0, 0);
        }
#pragma unroll
        for (int r = 0; r < 4; ++r) {
            const int e = kg * 4 + r;
            if (e < ce) {
                const float w1 = A[0][r] * B[0][r] * inv32;
                const float w2 = A[1][r] * B[1][r] * inv32;
                const float w3 = A[2][r] * B[2][r] * inv32;
                const float w4 = A[3][r] * B[3][r] * inv32;
                const int src = srcs[cur][e];
                const float sh0 = shl[cur][e][0], s1x = shl[cur][e][1];
                const float s1y = shl[cur][e][2], s1z = shl[cur][e][3];
                const half4 sx = *(const half4*)(selfx_h + (size_t)src * 512 + (u << 2));
                const float xs0 = (float)sx.x;
                const float xv0 = (float)sx.y;
                const float xv1 = (float)sx.z;
                const float xv2 = (float)sx.w;
                const float dv = xv0 * s1x + xv1 * s1y + xv2 * s1z;
                acc0 += 0.5f * (w1 * xs0 * sh0 + w4 * dv * R3);
                acc1 += C1V * (w2 * xs0 * s1x + w3 * xv0 * sh0);
                acc2 += C1V * (w2 * xs0 * s1y + w3 * xv1 * sh0);
                acc3 += C1V * (w2 * xs0 * s1z + w3 * xv2 * sh0);
            }
        }
        cur ^= 1;
    }
    flush(cur_dd);
    __syncthreads();

    // fused final irrep(Wo): M=16 (full now: DPB=16 rows), wave -> (matrix, col-tile half)
    {
        const int m = wid >> 1;
        const int ctg = (wid & 1) * 4;
        const _Float16* pW = (m == 0) ? pWo0 : pWo1;
        const f32x4 zero = {0.0f, 0.0f, 0.0f, 0.0f};
        f32x4 acc[4];
#pragma unroll
        for (int i = 0; i < 4; ++i) acc[i] = zero;
        for (int ks = 0; ks < 4; ++ks) {
            const half8 a = *(const half8*)&accP[m][lcol][ks * 32 + koff];
#pragma unroll
            for (int c2 = 0; c2 < 4; ++c2) {
                const int ct = ctg + c2;
                const half8 b = *(const half8*)(pW + (((ct * 4 + ks) * 64 + lane) << 3));
                acc[c2] = __builtin_amdgcn_mfma_f32_16x16x32_f16(a, b, acc[c2], 0, 0, 0);
            }
        }
#pragma unroll
        for (int c2 = 0; c2 < 4; ++c2) {
            const int col = (ctg + c2) * 16 + lcol;
            const float bb = (m == 0) ? bo0[col] : 0.0f;
#pragma unroll
            for (int r = 0; r < 4; ++r) {
                const int row = kg * 4 + r;
                const size_t g = (size_t)(dst0 + row) * 512;
                const float val = acc[c2][r] * RS128 + bb;
                if (m == 0) outacc[g + col] = val;
                else outacc[g + 128 + 3 * col + (m - 1)] = val;
            }
        }
    }
}

extern "C" void kernel_launch(void* const* d_in, const int* in_sizes, int n_in,
                              void* d_out, int out_size, void* d_ws, size_t ws_size,
                              hipStream_t stream) {
    const float* x = (const float*)d_in[0];
    const int* edge_index = (const int*)d_in[1];
    const float* edge_attr = (const float*)d_in[2];
    const float* edge_sh = (const float*)d_in[3];
    const float* Wp0 = (const float*)d_in[4];
    const float* bp0 = (const float*)d_in[5];
    const float* Wp1 = (const float*)d_in[6];
    const float* ngW1 = (const float*)d_in[7];
    const float* ngb1 = (const float*)d_in[8];
    const float* ngW2 = (const float*)d_in[9];
    const float* ngb2 = (const float*)d_in[10];
    const float* Wn0 = (const float*)d_in[11];
    const float* bn0 = (const float*)d_in[12];
    const float* Wn1 = (const float*)d_in[13];
    const float* fcnW1 = (const float*)d_in[14];
    const float* fcnW2 = (const float*)d_in[15];
    const float* l0W1 = (const float*)d_in[16];
    const float* l0W2 = (const float*)d_in[17];
    const float* Wo0 = (const float*)d_in[18];
    const float* bo0 = (const float*)d_in[19];
    const float* Wo1 = (const float*)d_in[20];

    float* out = (float*)d_out;
    _Float16* prexv_h = (_Float16*)d_out;    // first 10MB of d_out; dead before k_accum writes
    _Float16* selfx_h = (_Float16*)d_ws;     // [NN][128][4] interleaved
    int* deg = (int*)(selfx_h + (size_t)NN * 512);
    int* cursor = deg + NN;
    int* row_ptr = cursor + NN;
    int* csr_eid = row_ptr + NN + 1;
    float* pAB = (float*)(csr_eid + EE);
    __half* hh = (__half*)(pAB + (size_t)NN * 64);
    _Float16* Wf_t = (_Float16*)(hh + (size_t)EE * 64);
    _Float16* Wl_t = Wf_t + 512 * 32;
    _Float16* pWp0 = Wl_t + 512 * 32;
    _Float16* pWp1 = pWp0 + 128 * 128;
    _Float16* pWn0 = pWp1 + 128 * 128;
    _Float16* pWn1 = pWn0 + 128 * 128;
    _Float16* pWo0 = pWn1 + 128 * 128;
    _Float16* pWo1 = pWo0 + 128 * 128;
    _Float16* png1 = pWo1 + 128 * 128;
    _Float16* png2 = png1 + 256 * 256;
    _Float16* pWc  = png2 + 256 * 256;
    _Float16* pWa  = pWc + 128 * 32;
    _Float16* pWab = pWa + 32 * 32;

    k_packall<<<1091, 256, 0, stream>>>(Wp0, Wp1, Wn0, Wn1, Wo0, Wo1, ngW1, ngW2,
                                        l0W1, fcnW1, fcnW2, l0W2,
                                        pWp0, pWp1, pWn0, pWn1, pWo0, pWo1,
                                        png1, png2, pWc, pWa, Wf_t, Wl_t,
                                        pWab, deg);

    k_node<<<NN / 16, 256, 0, stream>>>(x, pWp0, bp0, pWp1, pWab,
                                        png1, ngb1, png2, ngb2, pWn0, bn0, pWn1,
                                        prexv_h, pAB, selfx_h);
    k_deg<<<EE / 256, 256, 0, stream>>>(edge_index, deg);
    k_scan<<<1, 1024, 0, stream>>>(deg, row_ptr);
    k_fill<<<EE / 256, 256, 0, stream>>>(edge_index, row_ptr, cursor, csr_eid);
    k_hidden_m<<<EE / 32, 256, 0, stream>>>(prexv_h, pAB, edge_index, edge_attr, csr_eid,
                                            pWc, pWa, hh);
    k_accum<<<NN / DPB, 512, 0, stream>>>(hh, selfx_h, edge_index, edge_sh, row_ptr, csr_eid,
                                          Wf_t, Wl_t, pWo0, bo0, pWo1, out);
}

// Round 20
// 248.085 us; speedup vs baseline: 1.4300x; 1.1503x over previous
//
#include <hip/hip_runtime.h>
#include <hip/hip_fp16.h>
#include <math.h>

#define NN 10000
#define EE 160000
#define DPB 8   // dsts per k_accum block

#define RS128 0.08838834764831845f   // 1/sqrt(128)
#define RS384 0.05103103630798287f   // 1/sqrt(384)
#define RS32  0.17677669529663687f   // 1/sqrt(32)
#define R3    0.57735026918962576f   // 1/sqrt(3)
#define C1V   0.86602540378443865f   // sqrt(3)/2

typedef _Float16 half8 __attribute__((ext_vector_type(8)));
typedef _Float16 half4 __attribute__((ext_vector_type(4)));
typedef float f32x4 __attribute__((ext_vector_type(4)));

__device__ __forceinline__ float sspf(float x) {
    return fmaxf(x, 0.0f) + log1pf(__expf(-fabsf(x))) - 0.69314718055994530942f;
}

__device__ __forceinline__ void packone(const float* __restrict__ W,
                                        _Float16* __restrict__ P,
                                        int K, int N, int off) {
    const int KS = K >> 5;
    int j = off & 7, lane = (off >> 3) & 63, rest = off >> 9;
    int ks = rest % KS, ct = rest / KS;
    int k = ks * 32 + ((lane >> 4) << 3) + j;
    int c = ct * 16 + (lane & 15);
    P[off] = (_Float16)W[k * N + c];
}

// ---- ALL weight packing + deg/cursor zeroing in one launch ----
__global__ __launch_bounds__(256) void k_packall(
    const float* __restrict__ Wp0, const float* __restrict__ Wp1,
    const float* __restrict__ Wn0, const float* __restrict__ Wn1,
    const float* __restrict__ Wo0, const float* __restrict__ Wo1,
    const float* __restrict__ ngW1, const float* __restrict__ ngW2,
    const float* __restrict__ l0W1, const float* __restrict__ fcnW1,
    const float* __restrict__ fcnW2, const float* __restrict__ l0W2,
    _Float16* __restrict__ pWp0, _Float16* __restrict__ pWp1,
    _Float16* __restrict__ pWn0, _Float16* __restrict__ pWn1,
    _Float16* __restrict__ pWo0, _Float16* __restrict__ pWo1,
    _Float16* __restrict__ png1, _Float16* __restrict__ png2,
    _Float16* __restrict__ pWc, _Float16* __restrict__ pWa,
    _Float16* __restrict__ Wf_t, _Float16* __restrict__ Wl_t,
    _Float16* __restrict__ pWab, int* __restrict__ degz) {
    int idx = blockIdx.x * 256 + threadIdx.x;
    if (idx < 98304) {
        int seg = idx >> 14, off = idx & 16383;
        if (seg == 0) packone(Wp0, pWp0, 128, 128, off);
        else if (seg == 1) packone(Wp1, pWp1, 128, 128, off);
        else if (seg == 2) packone(Wn0, pWn0, 128, 128, off);
        else if (seg == 3) packone(Wn1, pWn1, 128, 128, off);
        else if (seg == 4) packone(Wo0, pWo0, 128, 128, off);
        else packone(Wo1, pWo1, 128, 128, off);
    } else if (idx < 229376) {
        int r = idx - 98304;
        if (r < 65536) packone(ngW1, png1, 256, 256, r);
        else packone(ngW2, png2, 256, 256, r - 65536);
    } else if (idx < 233472) {
        packone(l0W1 + 256 * 32, pWc, 128, 32, idx - 229376);
    } else if (idx < 234496) {
        packone(fcnW1, pWa, 32, 32, idx - 233472);
    } else if (idx < 250880) {
        int off = idx - 234496;   // [0, 16384)
        int k = off & 31, c = off >> 5;
        Wf_t[c * 32 + k] = (_Float16)fcnW2[k * 512 + c];
        Wl_t[c * 32 + k] = (_Float16)l0W2[k * 512 + c];
    } else if (idx < 259072) {
        int off = idx - 250880;   // [0, 8192): pWab K=128, N=64 = [pA | pB]
        int j = off & 7, lane = (off >> 3) & 63, rest = off >> 9;
        int ks = rest & 3, ct = rest >> 2;
        int k = ks * 32 + ((lane >> 4) << 3) + j;
        int c = ct * 16 + (lane & 15);
        pWab[off] = (_Float16)((c < 32) ? l0W1[k * 32 + c]
                                        : l0W1[(128 + k) * 32 + (c - 32)]);
    } else if (idx < 279072) {
        degz[idx - 259072] = 0;   // deg + cursor (2*NN contiguous)
    }
}

// ---- MFMA irrep_linear: 16 nodes/block, 4 waves. In-place safe. (final pass) ----
__global__ __launch_bounds__(256) void k_irrep_m(
    const float* __restrict__ X, const _Float16* __restrict__ pW0,
    const float* __restrict__ b0, const _Float16* __restrict__ pW1,
    float* __restrict__ out) {
    __shared__ _Float16 Xr[4][16][136];
    const int t = threadIdx.x, lane = t & 63, w = t >> 6;
    const int nb = blockIdx.x * 16;
    for (int idx = t; idx < 16 * 128; idx += 256) {
        int n = idx >> 7, c4 = idx & 127;
        const float4 v = *(const float4*)(X + (size_t)(nb + n) * 512 + 4 * c4);
        float vals[4] = {v.x, v.y, v.z, v.w};
        int c = 4 * c4;
#pragma unroll
        for (int j = 0; j < 4; ++j) {
            int cc = c + j;
            if (cc < 128) Xr[0][n][cc] = (_Float16)vals[j];
            else { int d = cc - 128; Xr[1 + d % 3][n][d / 3] = (_Float16)vals[j]; }
        }
    }
    __syncthreads();
    const _Float16* pW = (w == 0) ? pW0 : pW1;
    const int row16 = lane & 15, kg = lane >> 4;
    f32x4 acc[8];
    const f32x4 zero = {0.0f, 0.0f, 0.0f, 0.0f};
#pragma unroll
    for (int ct = 0; ct < 8; ++ct) acc[ct] = zero;
    for (int ks = 0; ks < 4; ++ks) {
        const half8 a = *(const half8*)&Xr[w][row16][ks * 32 + kg * 8];
#pragma unroll
        for (int ct = 0; ct < 8; ++ct) {
            const half8 b = *(const half8*)(pW + (((ct * 4 + ks) * 64 + lane) << 3));
            acc[ct] = __builtin_amdgcn_mfma_f32_16x16x32_f16(a, b, acc[ct], 0, 0, 0);
        }
    }
#pragma unroll
    for (int ct = 0; ct < 8; ++ct) {
        const int col = ct * 16 + row16;
        const float bb = (w == 0) ? b0[col] : 0.0f;
#pragma unroll
        for (int r = 0; r < 4; ++r) {
            const int node = nb + kg * 4 + r;
            const float val = acc[ct][r] * RS128 + bb;
            if (w == 0) out[(size_t)node * 512 + col] = val;
            else out[(size_t)node * 512 + 128 + 3 * col + (w - 1)] = val;
        }
    }
}

// ---- FUSED node kernel: irrep(Wp)->prex (+pAB via MFMA) + norm_gate + irrep(Wn)->selfx_h ----
__global__ __launch_bounds__(256) void k_node(
    const float* __restrict__ X,
    const _Float16* __restrict__ pWp0, const float* __restrict__ bp0,
    const _Float16* __restrict__ pWp1, const _Float16* __restrict__ pWab,
    const _Float16* __restrict__ png1, const float* __restrict__ ngb1,
    const _Float16* __restrict__ png2, const float* __restrict__ ngb2,
    const _Float16* __restrict__ pWn0, const float* __restrict__ bn0,
    const _Float16* __restrict__ pWn1,
    float* __restrict__ prex, float* __restrict__ pAB,
    _Float16* __restrict__ selfx_h) {
    __shared__ _Float16 f0h[16][264];     // [0:128]=x_s, [128:256]=norms; later g
    __shared__ _Float16 t1h[16][264];     // prex_s stash for pAB; then t1
    __shared__ _Float16 xvh[3][16][136];
    const int t = threadIdx.x, lane = t & 63, w = t >> 6;
    const int nb = blockIdx.x * 16;
    const int row16 = lane & 15, kg = lane >> 4;
    const f32x4 zero = {0.0f, 0.0f, 0.0f, 0.0f};

    // stage x once
    for (int idx = t; idx < 16 * 128; idx += 256) {
        int n = idx >> 7, c4 = idx & 127;
        const float4 v = *(const float4*)(X + (size_t)(nb + n) * 512 + 4 * c4);
        float vals[4] = {v.x, v.y, v.z, v.w};
        int c = 4 * c4;
#pragma unroll
        for (int j = 0; j < 4; ++j) {
            int cc = c + j;
            if (cc < 128) f0h[n][cc] = (_Float16)vals[j];
            else { int d = cc - 128; xvh[d % 3][n][d / 3] = (_Float16)vals[j]; }
        }
    }
    __syncthreads();
    // norms
    for (int idx = t; idx < 16 * 128; idx += 256) {
        int n = idx >> 7, u = idx & 127;
        float a = (float)xvh[0][n][u], b = (float)xvh[1][n][u], c = (float)xvh[2][n][u];
        f0h[n][128 + u] = (_Float16)sqrtf(fmaf(a, a, fmaf(b, b, fmaf(c, c, 1e-12f))));
    }
    __syncthreads();
    // irrep(Wp) -> prex  (wave 0 also stashes prex_s fp16 into t1h)
    {
        const _Float16* pW = (w == 0) ? pWp0 : pWp1;
        f32x4 acc[8];
#pragma unroll
        for (int ct = 0; ct < 8; ++ct) acc[ct] = zero;
        for (int ks = 0; ks < 4; ++ks) {
            const half8 a = (w == 0)
                ? *(const half8*)&f0h[row16][ks * 32 + kg * 8]
                : *(const half8*)&xvh[w - 1][row16][ks * 32 + kg * 8];
#pragma unroll
            for (int ct = 0; ct < 8; ++ct) {
                const half8 b = *(const half8*)(pW + (((ct * 4 + ks) * 64 + lane) << 3));
                acc[ct] = __builtin_amdgcn_mfma_f32_16x16x32_f16(a, b, acc[ct], 0, 0, 0);
            }
        }
#pragma unroll
        for (int ct = 0; ct < 8; ++ct) {
            const int col = ct * 16 + row16;
            const float bb = (w == 0) ? bp0[col] : 0.0f;
#pragma unroll
            for (int r = 0; r < 4; ++r) {
                const int node = nb + kg * 4 + r;
                const float val = acc[ct][r] * RS128 + bb;
                if (w == 0) {
                    prex[(size_t)node * 512 + col] = val;
                    t1h[kg * 4 + r][col] = (_Float16)val;
                } else {
                    prex[(size_t)node * 512 + 128 + 3 * col + (w - 1)] = val;
                }
            }
        }
    }
    __syncthreads();
    // pAB = prex_s @ [l0W1[0:128] | l0W1[128:256]]  (wave w -> cols 16w..16w+15 of 64)
    {
        f32x4 acc = zero;
#pragma unroll
        for (int ks = 0; ks < 4; ++ks) {
            const half8 a = *(const half8*)&t1h[row16][ks * 32 + kg * 8];
            const half8 b = *(const half8*)(pWab + (((w * 4 + ks) * 64 + lane) << 3));
            acc = __builtin_amdgcn_mfma_f32_16x16x32_f16(a, b, acc, 0, 0, 0);
        }
        const int col = w * 16 + row16;
#pragma unroll
        for (int r = 0; r < 4; ++r)
            pAB[(size_t)(nb + kg * 4 + r) * 64 + col] = acc[r];
    }
    __syncthreads();
    // MLP1: t1 = silu(f0 @ ngW1 + b1)
    {
        f32x4 acc[4];
#pragma unroll
        for (int i = 0; i < 4; ++i) acc[i] = zero;
        for (int ks = 0; ks < 8; ++ks) {
            const half8 a = *(const half8*)&f0h[row16][ks * 32 + kg * 8];
#pragma unroll
            for (int c2 = 0; c2 < 4; ++c2) {
                const int ct = 4 * w + c2;
                const half8 b = *(const half8*)(png1 + (((ct * 8 + ks) * 64 + lane) << 3));
                acc[c2] = __builtin_amdgcn_mfma_f32_16x16x32_f16(a, b, acc[c2], 0, 0, 0);
            }
        }
        __syncthreads();   // t1h reads (pAB) done; safe to overwrite
#pragma unroll
        for (int c2 = 0; c2 < 4; ++c2) {
            const int col = (4 * w + c2) * 16 + row16;
            const float bb = ngb1[col];
#pragma unroll
            for (int r = 0; r < 4; ++r) {
                const float z = acc[c2][r] + bb;
                t1h[kg * 4 + r][col] = (_Float16)(z / (1.0f + __expf(-z)));
            }
        }
    }
    __syncthreads();
    // MLP2: g = t1 @ ngW2 + b2 -> f0h
    {
        f32x4 acc[4];
#pragma unroll
        for (int i = 0; i < 4; ++i) acc[i] = zero;
        for (int ks = 0; ks < 8; ++ks) {
            const half8 a = *(const half8*)&t1h[row16][ks * 32 + kg * 8];
#pragma unroll
            for (int c2 = 0; c2 < 4; ++c2) {
                const int ct = 4 * w + c2;
                const half8 b = *(const half8*)(png2 + (((ct * 8 + ks) * 64 + lane) << 3));
                acc[c2] = __builtin_amdgcn_mfma_f32_16x16x32_f16(a, b, acc[c2], 0, 0, 0);
            }
        }
        __syncthreads();   // f0h reads (MLP1 A) done; safe to overwrite
#pragma unroll
        for (int c2 = 0; c2 < 4; ++c2) {
            const int col = (4 * w + c2) * 16 + row16;
            const float bb = ngb2[col];
#pragma unroll
            for (int r = 0; r < 4; ++r)
                f0h[kg * 4 + r][col] = (_Float16)(acc[c2][r] + bb);
        }
    }
    __syncthreads();
    // gate vectors
    for (int idx = t; idx < 16 * 128; idx += 256) {
        int n = idx >> 7, u = idx & 127;
        const _Float16 g = f0h[n][128 + u];
        xvh[0][n][u] = xvh[0][n][u] * g;
        xvh[1][n][u] = xvh[1][n][u] * g;
        xvh[2][n][u] = xvh[2][n][u] * g;
    }
    __syncthreads();
    // irrep(Wn) -> selfx_h
    {
        const _Float16* pw = (w == 0) ? pWn0 : pWn1;
        f32x4 acc[8];
#pragma unroll
        for (int ct = 0; ct < 8; ++ct) acc[ct] = zero;
        for (int ks = 0; ks < 4; ++ks) {
            const half8 a = (w == 0)
                ? *(const half8*)&f0h[row16][ks * 32 + kg * 8]
                : *(const half8*)&xvh[w - 1][row16][ks * 32 + kg * 8];
#pragma unroll
            for (int ct = 0; ct < 8; ++ct) {
                const half8 b = *(const half8*)(pw + (((ct * 4 + ks) * 64 + lane) << 3));
                acc[ct] = __builtin_amdgcn_mfma_f32_16x16x32_f16(a, b, acc[ct], 0, 0, 0);
            }
        }
#pragma unroll
        for (int ct = 0; ct < 8; ++ct) {
            const int col = ct * 16 + row16;
            const float bb = (w == 0) ? bn0[col] : 0.0f;
#pragma unroll
            for (int r = 0; r < 4; ++r) {
                const int n = kg * 4 + r;
                const float val = acc[ct][r] * RS128 + bb;
                if (w == 0) f0h[n][col] = (_Float16)val;
                else xvh[w - 1][n][col] = (_Float16)val;
            }
        }
    }
    __syncthreads();
    for (int idx = t; idx < 16 * 128; idx += 256) {
        int n = idx >> 7, u = idx & 127;
        half4 sx = {f0h[n][u], xvh[0][n][u], xvh[1][n][u], xvh[2][n][u]};
        *(half4*)(selfx_h + (size_t)(nb + n) * 512 + (u << 2)) = sx;
    }
}

// ---- CSR build ----
__global__ __launch_bounds__(256) void k_deg(const int* __restrict__ ei, int* __restrict__ deg) {
    int e = blockIdx.x * 256 + threadIdx.x;
    if (e < EE) atomicAdd(&deg[ei[e]], 1);
}

__global__ __launch_bounds__(1024) void k_scan(const int* __restrict__ deg, int* __restrict__ row_ptr) {
    __shared__ int part[1024];
    const int t = threadIdx.x;
    const int base = t * 10;
    int loc[10];
    int s = 0;
#pragma unroll
    for (int i = 0; i < 10; ++i) {
        int idx = base + i;
        int d = (idx < NN) ? deg[idx] : 0;
        loc[i] = s;
        s += d;
    }
    part[t] = s;
    __syncthreads();
    for (int off = 1; off < 1024; off <<= 1) {
        int v = (t >= off) ? part[t - off] : 0;
        __syncthreads();
        part[t] += v;
        __syncthreads();
    }
    int excl = (t > 0) ? part[t - 1] : 0;
#pragma unroll
    for (int i = 0; i < 10; ++i) {
        int idx = base + i;
        if (idx <= NN) row_ptr[idx] = excl + loc[i];
    }
}

__global__ __launch_bounds__(256) void k_fill(const int* __restrict__ ei,
                                              const int* __restrict__ row_ptr,
                                              int* __restrict__ cursor,
                                              int* __restrict__ csr_eid) {
    int e = blockIdx.x * 256 + threadIdx.x;
    if (e < EE) {
        int d = ei[e];
        int pos = atomicAdd(&cursor[d], 1);
        csr_eid[row_ptr[d] + pos] = e;
    }
}

// ---- MFMA hidden units, CSR-position order ----
__global__ __launch_bounds__(256) void k_hidden_m(
    const float* __restrict__ prex, const float* __restrict__ pAB,
    const int* __restrict__ edge_index, const float* __restrict__ edge_attr,
    const int* __restrict__ csr_eid,
    const _Float16* __restrict__ pWc, const _Float16* __restrict__ pWa,
    __half* __restrict__ hh) {
    const int pb = blockIdx.x * 32;
    const int t = threadIdx.x, lane = t & 63, w = t >> 6;
    __shared__ _Float16 ipl[32][132];
    __shared__ _Float16 eal[32][36];
    __shared__ _Float16 h1o[32][32];
    __shared__ _Float16 hao[32][32];
    __shared__ int dsts[32], srcs[32], eids[32];

    if (t < 32) {
        const int id = csr_eid[pb + t];
        eids[t] = id;
        dsts[t] = edge_index[id];
        srcs[t] = edge_index[EE + id];
    }
    __syncthreads();
    for (int idx = t; idx < 32 * 32; idx += 256) {
        int e = idx >> 5, j = idx & 31;
        eal[e][j] = (_Float16)edge_attr[(size_t)eids[e] * 32 + j];
    }
    for (int idx = t; idx < 32 * 128; idx += 256) {
        int e = idx >> 7, u = idx & 127;
        const float* pd = prex + (size_t)dsts[e] * 512 + 128 + 3 * u;
        const float* ps = prex + (size_t)srcs[e] * 512 + 128 + 3 * u;
        ipl[e][u] = (_Float16)((pd[0] * ps[0] + pd[1] * ps[1] + pd[2] * ps[2]) * R3);
    }
    __syncthreads();

    const int row16 = lane & 15, kg = lane >> 4;
    const int mt = w >> 1, ct = w & 1;
    const int e0 = mt * 16;
    const f32x4 zero = {0.0f, 0.0f, 0.0f, 0.0f};
    const int kc = ct * 16 + row16;

    {
        f32x4 acc = zero;
#pragma unroll
        for (int ks = 0; ks < 4; ++ks) {
            const half8 a = *(const half8*)&ipl[e0 + row16][ks * 32 + kg * 8];
            const half8 b = *(const half8*)(pWc + (((ct * 4 + ks) * 64 + lane) << 3));
            acc = __builtin_amdgcn_mfma_f32_16x16x32_f16(a, b, acc, 0, 0, 0);
        }
#pragma unroll
        for (int r = 0; r < 4; ++r) {
            const int e = e0 + kg * 4 + r;
            const float v = acc[r] + pAB[(size_t)dsts[e] * 64 + kc]
                                   + pAB[(size_t)srcs[e] * 64 + 32 + kc];
            h1o[e][kc] = (_Float16)sspf(v * RS384);
        }
    }
    {
        const half8 a = *(const half8*)&eal[e0 + row16][kg * 8];
        const half8 b = *(const half8*)(pWa + ((ct * 64 + lane) << 3));
        f32x4 acc = __builtin_amdgcn_mfma_f32_16x16x32_f16(a, b, zero, 0, 0, 0);
#pragma unroll
        for (int r = 0; r < 4; ++r) {
            const int e = e0 + kg * 4 + r;
            hao[e][kc] = (_Float16)sspf((float)acc[r] * RS32);
        }
    }
    __syncthreads();
    for (int idx = t; idx < 32 * 32; idx += 256) {
        const int e = idx >> 5, j = idx & 31;
        unsigned vv;
        if (j < 16) {
            __half2 h2 = __halves2half2((__half)h1o[e][2 * j], (__half)h1o[e][2 * j + 1]);
            vv = *(unsigned*)&h2;
        } else {
            const int jj = j - 16;
            __half2 h2 = __halves2half2((__half)hao[e][2 * jj], (__half)hao[e][2 * jj + 1]);
            vv = *(unsigned*)&h2;
        }
        ((unsigned*)hh)[(size_t)(pb + e) * 32 + j] = vv;
    }
}

// ---- per-dst accumulate via MFMA; r13 pipeline (proven 108 us) ----
__global__ __launch_bounds__(512) void k_accum(
    const __half* __restrict__ hh, const _Float16* __restrict__ selfx_h,
    const int* __restrict__ edge_index, const float* __restrict__ edge_sh,
    const int* __restrict__ row_ptr, const int* __restrict__ csr_eid,
    const _Float16* __restrict__ Wf_t, const _Float16* __restrict__ Wl_t,
    float* __restrict__ outacc) {
    const int dst0 = blockIdx.x * DPB;
    const int t = threadIdx.x;
    const int lane = t & 63;
    const int wid = t >> 6;
    const int lcol = lane & 15;
    const int kg = lane >> 4;
    const int u = 16 * wid + lcol;
    const int koff = kg * 8;

    __shared__ __align__(16) _Float16 h1s[2][4][16][8];
    __shared__ __align__(16) _Float16 has[2][4][16][8];
    __shared__ float shl[2][16][4];
    __shared__ int srcs[2][16];
    __shared__ int cbeg[DPB], cne[DPB], cchk[DPB + 1];

    if (t < DPB) {
        const int b = row_ptr[dst0 + t];
        cbeg[t] = b;
        cne[t] = row_ptr[dst0 + t + 1] - b;
    }
    __syncthreads();
    if (t == 0) {
        int s = 0;
#pragma unroll
        for (int i = 0; i < DPB; ++i) { cchk[i] = s; s += max(1, (cne[i] + 15) >> 4); }
        cchk[DPB] = s;
    }
    half8 bf[4], bl[4];
#pragma unroll
    for (int q = 0; q < 4; ++q) {
        const int col = q * 128 + u;
        bf[q] = *(const half8*)(Wf_t + col * 32 + koff);
        bl[q] = *(const half8*)(Wl_t + col * 32 + koff);
    }
    __syncthreads();
    const int nc = cchk[DPB];
    const float inv32 = 1.0f / 32.0f;

    float acc0 = 0, acc1 = 0, acc2 = 0, acc3 = 0;

    unsigned rhh = 0;
    int rsrc = 0;
    float4 rsh = {0.0f, 0.0f, 0.0f, 0.0f};

    const int se = t >> 5, sw = t & 31;

    auto issue = [&](int ci) {
        int dd = 0;
        while (dd + 1 < DPB && ci >= cchk[dd + 1]) ++dd;
        const int c0 = (ci - cchk[dd]) << 4;
        const int ce = min(16, cne[dd] - c0);
        const int pos = cbeg[dd] + c0;
        rhh = (se < ce) ? ((const unsigned*)hh)[(size_t)(pos + se) * 32 + sw] : 0u;
        if (t < 16) {
            if (t < ce) {
                const int id = csr_eid[pos + t];
                rsrc = edge_index[EE + id];
                rsh = *(const float4*)(edge_sh + (size_t)id * 4);
            } else {
                rsrc = 0;
                rsh = make_float4(0.0f, 0.0f, 0.0f, 0.0f);
            }
        }
    };

    auto flush = [&](int dd) {
        acc0 += __shfl_xor(acc0, 16, 64); acc0 += __shfl_xor(acc0, 32, 64);
        acc1 += __shfl_xor(acc1, 16, 64); acc1 += __shfl_xor(acc1, 32, 64);
        acc2 += __shfl_xor(acc2, 16, 64); acc2 += __shfl_xor(acc2, 32, 64);
        acc3 += __shfl_xor(acc3, 16, 64); acc3 += __shfl_xor(acc3, 32, 64);
        if (lane < 16) {
            const size_t g = (size_t)(dst0 + dd) * 512;
            const half4 sx = *(const half4*)(selfx_h + g + (u << 2));
            outacc[g + u] = acc0 + (float)sx.x;
            outacc[g + 128 + 3 * u + 0] = acc1 + (float)sx.y;
            outacc[g + 128 + 3 * u + 1] = acc2 + (float)sx.z;
            outacc[g + 128 + 3 * u + 2] = acc3 + (float)sx.w;
        }
        acc0 = acc1 = acc2 = acc3 = 0;
    };

    issue(0);
    int cur = 0, cur_dd = 0;
    for (int ci = 0; ci < nc; ++ci) {
        if (sw < 16) ((unsigned*)h1s[cur])[(sw >> 2) * 64 + se * 4 + (sw & 3)] = rhh;
        else         ((unsigned*)has[cur])[((sw - 16) >> 2) * 64 + se * 4 + ((sw - 16) & 3)] = rhh;
        if (t < 16) {
            srcs[cur][t] = rsrc;
            shl[cur][t][0] = rsh.x; shl[cur][t][1] = rsh.y;
            shl[cur][t][2] = rsh.z; shl[cur][t][3] = rsh.w;
        }
        int dd = 0;
        while (dd + 1 < DPB && ci >= cchk[dd + 1]) ++dd;
        const int c0 = (ci - cchk[dd]) << 4;
        const int ce = min(16, cne[dd] - c0);
        if (ci + 1 < nc) issue(ci + 1);
        __syncthreads();
        if (dd != cur_dd) { flush(cur_dd); cur_dd = dd; }

        const half8 haf = *(const half8*)(&has[cur][kg][lcol][0]);
        const half8 h1f = *(const half8*)(&h1s[cur][kg][lcol][0]);
        const f32x4 zero = {0.0f, 0.0f, 0.0f, 0.0f};
        f32x4 A[4], B[4];
#pragma unroll
        for (int q = 0; q < 4; ++q) {
            A[q] = __builtin_amdgcn_mfma_f32_16x16x32_f16(haf, bf[q], zero, 0, 0, 0);
            B[q] = __builtin_amdgcn_mfma_f32_16x16x32_f16(h1f, bl[q], zero, 0, 0, 0);
        }
#pragma unroll
        for (int r = 0; r < 4; ++r) {
            const int e = kg * 4 + r;
            if (e < ce) {
                const float w1 = A[0][r] * B[0][r] * inv32;
                const float w2 = A[1][r] * B[1][r] * inv32;
                const float w3 = A[2][r] * B[2][r] * inv32;
                const float w4 = A[3][r] * B[3][r] * inv32;
                const int src = srcs[cur][e];
                const float sh0 = shl[cur][e][0], s1x = shl[cur][e][1];
                const float s1y = shl[cur][e][2], s1z = shl[cur][e][3];
                const half4 sx = *(const half4*)(selfx_h + (size_t)src * 512 + (u << 2));
                const float xs0 = (float)sx.x;
                const float xv0 = (float)sx.y;
                const float xv1 = (float)sx.z;
                const float xv2 = (float)sx.w;
                const float dv = xv0 * s1x + xv1 * s1y + xv2 * s1z;
                acc0 += 0.5f * (w1 * xs0 * sh0 + w4 * dv * R3);
                acc1 += C1V * (w2 * xs0 * s1x + w3 * xv0 * sh0);
                acc2 += C1V * (w2 * xs0 * s1y + w3 * xv1 * sh0);
                acc3 += C1V * (w2 * xs0 * s1z + w3 * xv2 * sh0);
            }
        }
        cur ^= 1;
    }
    flush(cur_dd);
}

extern "C" void kernel_launch(void* const* d_in, const int* in_sizes, int n_in,
                              void* d_out, int out_size, void* d_ws, size_t ws_size,
                              hipStream_t stream) {
    const float* x = (const float*)d_in[0];
    const int* edge_index = (const int*)d_in[1];
    const float* edge_attr = (const float*)d_in[2];
    const float* edge_sh = (const float*)d_in[3];
    const float* Wp0 = (const float*)d_in[4];
    const float* bp0 = (const float*)d_in[5];
    const float* Wp1 = (const float*)d_in[6];
    const float* ngW1 = (const float*)d_in[7];
    const float* ngb1 = (const float*)d_in[8];
    const float* ngW2 = (const float*)d_in[9];
    const float* ngb2 = (const float*)d_in[10];
    const float* Wn0 = (const float*)d_in[11];
    const float* bn0 = (const float*)d_in[12];
    const float* Wn1 = (const float*)d_in[13];
    const float* fcnW1 = (const float*)d_in[14];
    const float* fcnW2 = (const float*)d_in[15];
    const float* l0W1 = (const float*)d_in[16];
    const float* l0W2 = (const float*)d_in[17];
    const float* Wo0 = (const float*)d_in[18];
    const float* bo0 = (const float*)d_in[19];
    const float* Wo1 = (const float*)d_in[20];

    float* out = (float*)d_out;
    float* prex = out;                       // d_out as pre_x scratch; k_accum overwrites it
    _Float16* selfx_h = (_Float16*)d_ws;     // [NN][128][4] interleaved {s,vx,vy,vz}
    int* deg = (int*)(selfx_h + (size_t)NN * 512);
    int* cursor = deg + NN;
    int* row_ptr = cursor + NN;
    int* csr_eid = row_ptr + NN + 1;
    float* pAB = (float*)(csr_eid + EE);
    __half* hh = (__half*)(pAB + (size_t)NN * 64);
    _Float16* Wf_t = (_Float16*)(hh + (size_t)EE * 64);
    _Float16* Wl_t = Wf_t + 512 * 32;
    _Float16* pWp0 = Wl_t + 512 * 32;
    _Float16* pWp1 = pWp0 + 128 * 128;
    _Float16* pWn0 = pWp1 + 128 * 128;
    _Float16* pWn1 = pWn0 + 128 * 128;
    _Float16* pWo0 = pWn1 + 128 * 128;
    _Float16* pWo1 = pWo0 + 128 * 128;
    _Float16* png1 = pWo1 + 128 * 128;
    _Float16* png2 = png1 + 256 * 256;
    _Float16* pWc  = png2 + 256 * 256;
    _Float16* pWa  = pWc + 128 * 32;
    _Float16* pWab = pWa + 32 * 32;

    k_packall<<<1091, 256, 0, stream>>>(Wp0, Wp1, Wn0, Wn1, Wo0, Wo1, ngW1, ngW2,
                                        l0W1, fcnW1, fcnW2, l0W2,
                                        pWp0, pWp1, pWn0, pWn1, pWo0, pWo1,
                                        png1, png2, pWc, pWa, Wf_t, Wl_t,
                                        pWab, deg);

    k_node<<<NN / 16, 256, 0, stream>>>(x, pWp0, bp0, pWp1, pWab,
                                        png1, ngb1, png2, ngb2, pWn0, bn0, pWn1,
                                        prex, pAB, selfx_h);
    k_deg<<<EE / 256, 256, 0, stream>>>(edge_index, deg);
    k_scan<<<1, 1024, 0, stream>>>(deg, row_ptr);
    k_fill<<<EE / 256, 256, 0, stream>>>(edge_index, row_ptr, cursor, csr_eid);
    k_hidden_m<<<EE / 32, 256, 0, stream>>>(prex, pAB, edge_index, edge_attr, csr_eid,
                                            pWc, pWa, hh);
    k_accum<<<NN / DPB, 512, 0, stream>>>(hh, selfx_h, edge_index, edge_sh, row_ptr, csr_eid,
                                          Wf_t, Wl_t, out);
    k_irrep_m<<<NN / 16, 256, 0, stream>>>(out, pWo0, bo0, pWo1, out);
}